// Round 14
// baseline (856.980 us; speedup 1.0000x reference)
//
#include <hip/hip_runtime.h>

#define LL 32
#define HH 64
#define PZS 68  // padded stride for transposed-dz slab (rows 16B-aligned, <=4-way conflict)

typedef __attribute__((ext_vector_type(4))) float f32x4;

template <int CTRL>
__device__ __forceinline__ float dpp_add_step(float x) {
  int y = __builtin_amdgcn_update_dpp(0, __builtin_bit_cast(int, x), CTRL, 0xf, 0xf, true);
  return x + __builtin_bit_cast(float, y);
}

// 64-lane sum -> uniform value (via readlane 63). Used once per sample at end.
__device__ __forceinline__ float wave_sum64(float x) {
  x = dpp_add_step<0x111>(x);  // row_shr:1
  x = dpp_add_step<0x112>(x);  // row_shr:2
  x = dpp_add_step<0x114>(x);  // row_shr:4
  x = dpp_add_step<0x118>(x);  // row_shr:8
  x = dpp_add_step<0x142>(x);  // row_bcast15
  x = dpp_add_step<0x143>(x);  // row_bcast31
  return __builtin_bit_cast(float, __builtin_amdgcn_readlane(__builtin_bit_cast(int, x), 63));
}

// Wave-uniform broadcast of lane l's value — the LDS-free hv transport.
__device__ __forceinline__ float rlbc(float v, int l) {
  return __builtin_bit_cast(float, __builtin_amdgcn_readlane(__builtin_bit_cast(int, v), l));
}

#define DECL_W(n) float w_##n = Wc[n * HH + lane];

// Dual-sample dot slice: samples A and B interleaved per weight. Chain A's
// readlane->fma dependency stall is filled by chain B's independent pair
// (R11 lesson: wall is latency-bound at 766 cyc/step with only 64% VALU busy;
// issue-shaving was neutral -> add independent work instead).
#define MV4D(i0, i1, i2, i3)                   \
  a0A = fmaf(rlbc(hvA, i0), w_##i0, a0A);      \
  a0B = fmaf(rlbc(hvB, i0), w_##i0, a0B);      \
  a1A = fmaf(rlbc(hvA, i1), w_##i1, a1A);      \
  a1B = fmaf(rlbc(hvB, i1), w_##i1, a1B);      \
  a2A = fmaf(rlbc(hvA, i2), w_##i2, a2A);      \
  a2B = fmaf(rlbc(hvB, i2), w_##i2, a2B);      \
  a3A = fmaf(rlbc(hvA, i3), w_##i3, a3A);      \
  a3B = fmaf(rlbc(hvB, i3), w_##i3, a3B);

// In-loop weight pin (prior session: removing it regressed 395->463).
#define PIN_ALL_W                                                              \
  asm volatile(""                                                              \
               : "+v"(w_0), "+v"(w_1), "+v"(w_2), "+v"(w_3), "+v"(w_4),       \
                 "+v"(w_5), "+v"(w_6), "+v"(w_7), "+v"(w_8), "+v"(w_9),       \
                 "+v"(w_10), "+v"(w_11), "+v"(w_12), "+v"(w_13), "+v"(w_14),  \
                 "+v"(w_15), "+v"(w_16), "+v"(w_17), "+v"(w_18), "+v"(w_19),  \
                 "+v"(w_20), "+v"(w_21), "+v"(w_22), "+v"(w_23), "+v"(w_24),  \
                 "+v"(w_25), "+v"(w_26), "+v"(w_27), "+v"(w_28), "+v"(w_29),  \
                 "+v"(w_30), "+v"(w_31), "+v"(w_32), "+v"(w_33), "+v"(w_34),  \
                 "+v"(w_35), "+v"(w_36), "+v"(w_37), "+v"(w_38), "+v"(w_39),  \
                 "+v"(w_40), "+v"(w_41), "+v"(w_42), "+v"(w_43), "+v"(w_44),  \
                 "+v"(w_45), "+v"(w_46), "+v"(w_47), "+v"(w_48), "+v"(w_49),  \
                 "+v"(w_50), "+v"(w_51), "+v"(w_52), "+v"(w_53), "+v"(w_54),  \
                 "+v"(w_55), "+v"(w_56), "+v"(w_57), "+v"(w_58), "+v"(w_59),  \
                 "+v"(w_60), "+v"(w_61), "+v"(w_62), "+v"(w_63), "+v"(win0),  \
                 "+v"(win1), "+v"(bcj), "+v"(dwout));

// TWO samples per wave, 512 blocks. Weights are shared across samples, so the
// second recurrence costs only ~15 VGPRs and its issue fills the first one's
// dependency stalls. No barriers (single wave owns everything).
__global__ __launch_bounds__(64, 1) void rnn2d_kernel(
    const int* __restrict__ x, const float* __restrict__ Win,
    const float* __restrict__ Wc, const float* __restrict__ bc,
    const float* __restrict__ Wout, const float* __restrict__ bout,
    float* __restrict__ out) {
  const int lane = threadIdx.x;
  const int b0 = blockIdx.x * 2;
  const int b1 = b0 + 1;
  __shared__ float vrow[2 * LL * HH];  // vertical carry, per sample slot
  __shared__ float pz[2 * LL * PZS];   // transposed dz slab, per sample slot
  float* vrowA = vrow;
  float* vrowB = vrow + LL * HH;
  float* pzA = pz;
  float* pzB = pz + LL * PZS;

  DECL_W(0)  DECL_W(1)  DECL_W(2)  DECL_W(3)  DECL_W(4)  DECL_W(5)  DECL_W(6)  DECL_W(7)
  DECL_W(8)  DECL_W(9)  DECL_W(10) DECL_W(11) DECL_W(12) DECL_W(13) DECL_W(14) DECL_W(15)
  DECL_W(16) DECL_W(17) DECL_W(18) DECL_W(19) DECL_W(20) DECL_W(21) DECL_W(22) DECL_W(23)
  DECL_W(24) DECL_W(25) DECL_W(26) DECL_W(27) DECL_W(28) DECL_W(29) DECL_W(30) DECL_W(31)
  DECL_W(32) DECL_W(33) DECL_W(34) DECL_W(35) DECL_W(36) DECL_W(37) DECL_W(38) DECL_W(39)
  DECL_W(40) DECL_W(41) DECL_W(42) DECL_W(43) DECL_W(44) DECL_W(45) DECL_W(46) DECL_W(47)
  DECL_W(48) DECL_W(49) DECL_W(50) DECL_W(51) DECL_W(52) DECL_W(53) DECL_W(54) DECL_W(55)
  DECL_W(56) DECL_W(57) DECL_W(58) DECL_W(59) DECL_W(60) DECL_W(61) DECL_W(62) DECL_W(63)

  float win0 = Win[lane];
  float win1 = Win[HH + lane];
  float bcj = bc[lane];
  float dwout = Wout[lane * 2 + 1] - Wout[lane * 2 + 0];
  const float dbout = bout[1] - bout[0];

  // Row 0 sees zero vertical hidden carry (both samples).
#pragma unroll
  for (int c0 = 0; c0 < 2 * LL; ++c0) vrow[c0 * HH + lane] = 0.f;

  const int* xb0 = x + b0 * (LL * LL);
  const int* xb1 = x + b1 * (LL * LL);
  unsigned prevmaskA = 0u, prevmaskB = 0u;
  int spvA = (lane < LL) ? xb0[lane] : 0;  // prefetched row-0 spins
  int spvB = (lane < LL) ? xb1[lane] : 0;
  float totalA = 0.f, totalB = 0.f;  // per-lane partials of sum(logp)
  float hvA = 0.f, hvB = 0.f;        // register-resident recurrences

#pragma unroll 1
  for (int r = 0; r < LL; ++r) {
    const unsigned curmaskA =
        (unsigned)(__ballot(lane < LL && spvA) & 0xffffffffull);
    const unsigned curmaskB =
        (unsigned)(__ballot(lane < LL && spvB) & 0xffffffffull);
    if (r < LL - 1) {
      spvA = (lane < LL) ? xb0[(r + 1) * LL + lane] : 0;
      spvB = (lane < LL) ? xb1[(r + 1) * LL + lane] : 0;
    }

    const int odd = r & 1;
    const int d = odd ? -1 : 1;  // boustrophedon direction
    int c = odd ? (LL - 1) : 0;  // spatial column of scan step 0

#pragma unroll 2
    for (int k = 0; k < LL; ++k) {
      PIN_ALL_W

      // Prefetch next step's vertical carries (off both serial chains).
      const int cn = (c + d) & (LL - 1);
      const float vjnA = vrowA[cn * HH + lane];
      const float vjnB = vrowB[cn * HH + lane];

      // Dual 64-deep dots: 128 readlanes + 128 FMAs, A/B interleaved.
      float a0A = 0.f, a1A = 0.f, a2A = 0.f, a3A = 0.f;
      float a0B = 0.f, a1B = 0.f, a2B = 0.f, a3B = 0.f;
      MV4D(0, 1, 2, 3)      MV4D(4, 5, 6, 7)      MV4D(8, 9, 10, 11)
      MV4D(12, 13, 14, 15)  MV4D(16, 17, 18, 19)  MV4D(20, 21, 22, 23)
      MV4D(24, 25, 26, 27)  MV4D(28, 29, 30, 31)  MV4D(32, 33, 34, 35)
      MV4D(36, 37, 38, 39)  MV4D(40, 41, 42, 43)  MV4D(44, 45, 46, 47)
      MV4D(48, 49, 50, 51)  MV4D(52, 53, 54, 55)  MV4D(56, 57, 58, 59)
      MV4D(60, 61, 62, 63)

      // newR @ Win one-hot selects, per sample (wave-uniform mask bits).
      float wincA = 0.f, wincB = 0.f;
      if (k > 0) {
        const int cp = (c - d) & 31;
        wincA += ((curmaskA >> cp) & 1u) ? win1 : win0;
        wincB += ((curmaskB >> cp) & 1u) ? win1 : win0;
      }
      if (r > 0) {
        wincA += ((prevmaskA >> c) & 1u) ? win1 : win0;
        wincB += ((prevmaskB >> c) & 1u) ? win1 : win0;
      }

      const float preA = ((a0A + a1A) + (a2A + a3A)) + bcj + wincA;
      const float preB = ((a0B + a1B) + (a2B + a3B)) + bcj + wincB;
      const float hnewA = preA > 0.f ? preA : (__expf(preA) - 1.f);  // elu
      const float hnewB = preB > 0.f ? preB : (__expf(preB) - 1.f);

      vrowA[c * HH + lane] = hnewA;         // vertical carries (off-chain)
      vrowB[c * HH + lane] = hnewB;
      pzA[k * PZS + lane] = hnewA * dwout;  // deferred-dz contributions
      pzB[k * PZS + lane] = hnewB * dwout;

      // hv for next step stays in-register; at k==31 next step is next row's
      // step 0 (same column, zero horizontal carry).
      hvA = hnewA + ((k < LL - 1) ? vjnA : 0.f);
      hvB = hnewB + ((k < LL - 1) ? vjnB : 0.f);

      c = cn;
    }
    prevmaskA = curmaskA;
    prevmaskB = curmaskB;

    // Row epilogue: transposed reductions (lane t sums pz row t&31).
    {
      const int kk = lane & 31;
      const float* pzrA = pzA + kk * PZS;
      const float* pzrB = pzB + kk * PZS;
      float s0A = 0.f, s1A = 0.f, s2A = 0.f, s3A = 0.f;
      float s0B = 0.f, s1B = 0.f, s2B = 0.f, s3B = 0.f;
#pragma unroll
      for (int g = 0; g < 16; ++g) {
        const f32x4 vA = *(const f32x4*)(pzrA + 4 * g);
        const f32x4 vB = *(const f32x4*)(pzrB + 4 * g);
        s0A += vA[0]; s1A += vA[1]; s2A += vA[2]; s3A += vA[3];
        s0B += vB[0]; s1B += vB[1]; s2B += vB[2]; s3B += vB[3];
      }
      const float dzA = ((s0A + s1A) + (s2A + s3A)) + dbout;
      const float dzB = ((s0B + s1B) + (s2B + s3B)) + dbout;
      const int ck = odd ? (LL - 1 - kk) : kk;  // spatial column of step kk
      const unsigned spinA = (curmaskA >> ck) & 1u;
      const unsigned spinB = (curmaskB >> ck) & 1u;
      const float ttA = __builtin_bit_cast(
          float, __builtin_bit_cast(unsigned, dzA) ^ (spinA << 31));
      const float ttB = __builtin_bit_cast(
          float, __builtin_bit_cast(unsigned, dzB) ^ (spinB << 31));
      float lpvA = -(fmaxf(ttA, 0.f) + __logf(1.f + __expf(-fabsf(ttA))));
      float lpvB = -(fmaxf(ttB, 0.f) + __logf(1.f + __expf(-fabsf(ttB))));
      lpvA = (lpvA == lpvA) ? lpvA : -35.0f;  // nan_to_num(nan=-35)
      lpvB = (lpvB == lpvB) ? lpvB : -35.0f;
      totalA += (lane < LL) ? lpvA : 0.f;
      totalB += (lane < LL) ? lpvB : 0.f;
    }
  }

  const float grandA = wave_sum64(totalA);
  const float grandB = wave_sum64(totalB);
  if (lane == 0) {
    out[b0] = 0.5f * grandA;  // LOGP_FACTOR * sum
    out[b1] = 0.5f * grandB;
  }
}

extern "C" void kernel_launch(void* const* d_in, const int* in_sizes, int n_in,
                              void* d_out, int out_size, void* d_ws, size_t ws_size,
                              hipStream_t stream) {
  const int* x = (const int*)d_in[0];
  const float* Win = (const float*)d_in[1];
  const float* Wc = (const float*)d_in[2];
  const float* bc = (const float*)d_in[3];
  const float* Wout = (const float*)d_in[4];
  const float* bout = (const float*)d_in[5];
  float* out = (float*)d_out;
  rnn2d_kernel<<<dim3((out_size + 1) / 2), dim3(64), 0, stream>>>(x, Win, Wc, bc, Wout, bout, out);
}

// Round 18
// 361.574 us; speedup vs baseline: 2.3701x; 2.3701x over previous
//
#include <hip/hip_runtime.h>

#define LL 32
#define HH 64
#define PZS 68  // padded stride for transposed-dz slab (rows 16B-aligned, <=4-way conflict)

typedef __attribute__((ext_vector_type(4))) float f32x4;

template <int CTRL>
__device__ __forceinline__ float dpp_add_step(float x) {
  int y = __builtin_amdgcn_update_dpp(0, __builtin_bit_cast(int, x), CTRL, 0xf, 0xf, true);
  return x + __builtin_bit_cast(float, y);
}

// 64-lane sum -> uniform value (via readlane 63). Used once at kernel end.
__device__ __forceinline__ float wave_sum64(float x) {
  x = dpp_add_step<0x111>(x);  // row_shr:1
  x = dpp_add_step<0x112>(x);  // row_shr:2
  x = dpp_add_step<0x114>(x);  // row_shr:4
  x = dpp_add_step<0x118>(x);  // row_shr:8
  x = dpp_add_step<0x142>(x);  // row_bcast15
  x = dpp_add_step<0x143>(x);  // row_bcast31
  return __builtin_bit_cast(float, __builtin_amdgcn_readlane(__builtin_bit_cast(int, x), 63));
}

// Wave-uniform broadcast of lane l's value (VALU pipe, ~5.3 cyc measured
// R5/R11 — quarter-rate, which is why the ALL-readlane kernel walls at 762
// cyc/step and why R14's dual-sample ILP doubled cost instead of hiding it).
__device__ __forceinline__ float rlbc(float v, int l) {
  return __builtin_bit_cast(float, __builtin_amdgcn_readlane(__builtin_bit_cast(int, v), l));
}

#define DECL_W(n) float w_##n = Wc[n * HH + lane];

// Readlane half of the dot: i in [0,32). Ascending i per accumulator chain
// (a0: 0,4,..,28 then 32,..,60 from the LDS half) == R11's order exactly ->
// bit-identical results.
#define MV4R(i0, i1, i2, i3)                 \
  a0 = fmaf(rlbc(hv, i0), w_##i0, a0);       \
  a1 = fmaf(rlbc(hv, i1), w_##i1, a1);       \
  a2 = fmaf(rlbc(hv, i2), w_##i2, a2);       \
  a3 = fmaf(rlbc(hv, i3), w_##i3, a3);

// LDS half of the dot: group n holds hv[32+4n .. 32+4n+3] (uniform regs).
#define MV4L(n, i0, i1, i2, i3)       \
  a0 = fmaf(g##n[0], w_##i0, a0);     \
  a1 = fmaf(g##n[1], w_##i1, a1);     \
  a2 = fmaf(g##n[2], w_##i2, a2);     \
  a3 = fmaf(g##n[3], w_##i3, a3);

#define LOADG(n) f32x4 g##n = hv4[n];

// In-loop weight pin (prior session: removing it regressed 395->463).
#define PIN_ALL_W                                                              \
  asm volatile(""                                                              \
               : "+v"(w_0), "+v"(w_1), "+v"(w_2), "+v"(w_3), "+v"(w_4),       \
                 "+v"(w_5), "+v"(w_6), "+v"(w_7), "+v"(w_8), "+v"(w_9),       \
                 "+v"(w_10), "+v"(w_11), "+v"(w_12), "+v"(w_13), "+v"(w_14),  \
                 "+v"(w_15), "+v"(w_16), "+v"(w_17), "+v"(w_18), "+v"(w_19),  \
                 "+v"(w_20), "+v"(w_21), "+v"(w_22), "+v"(w_23), "+v"(w_24),  \
                 "+v"(w_25), "+v"(w_26), "+v"(w_27), "+v"(w_28), "+v"(w_29),  \
                 "+v"(w_30), "+v"(w_31), "+v"(w_32), "+v"(w_33), "+v"(w_34),  \
                 "+v"(w_35), "+v"(w_36), "+v"(w_37), "+v"(w_38), "+v"(w_39),  \
                 "+v"(w_40), "+v"(w_41), "+v"(w_42), "+v"(w_43), "+v"(w_44),  \
                 "+v"(w_45), "+v"(w_46), "+v"(w_47), "+v"(w_48), "+v"(w_49),  \
                 "+v"(w_50), "+v"(w_51), "+v"(w_52), "+v"(w_53), "+v"(w_54),  \
                 "+v"(w_55), "+v"(w_56), "+v"(w_57), "+v"(w_58), "+v"(w_59),  \
                 "+v"(w_60), "+v"(w_61), "+v"(w_62), "+v"(w_63), "+v"(win0),  \
                 "+v"(win1), "+v"(bcj), "+v"(dwout));

// One wave per sample, 1024 blocks (R14: 512-block 2-sample layout = 815 µs,
// reverted). Hybrid hv transport: i<32 via readlane (VALU), i>=32 via uniform
// ds_read_b128 (LDS pipe) whose write->read turnaround hides under the
// readlane phase. DS ops are same-wave in-order, so no barriers needed.
__global__ __launch_bounds__(64, 1) void rnn2d_kernel(
    const int* __restrict__ x, const float* __restrict__ Win,
    const float* __restrict__ Wc, const float* __restrict__ bc,
    const float* __restrict__ Wout, const float* __restrict__ bout,
    float* __restrict__ out) {
  const int lane = threadIdx.x;
  const int b = blockIdx.x;
  __shared__ float vrow[LL * HH];   // vertical carry [column][hidden]
  __shared__ float pz[LL * PZS];    // transposed dz slab [step][hidden]
  __shared__ __align__(16) float hvbuf[2 * HH];  // hv double buffer (parity)

  DECL_W(0)  DECL_W(1)  DECL_W(2)  DECL_W(3)  DECL_W(4)  DECL_W(5)  DECL_W(6)  DECL_W(7)
  DECL_W(8)  DECL_W(9)  DECL_W(10) DECL_W(11) DECL_W(12) DECL_W(13) DECL_W(14) DECL_W(15)
  DECL_W(16) DECL_W(17) DECL_W(18) DECL_W(19) DECL_W(20) DECL_W(21) DECL_W(22) DECL_W(23)
  DECL_W(24) DECL_W(25) DECL_W(26) DECL_W(27) DECL_W(28) DECL_W(29) DECL_W(30) DECL_W(31)
  DECL_W(32) DECL_W(33) DECL_W(34) DECL_W(35) DECL_W(36) DECL_W(37) DECL_W(38) DECL_W(39)
  DECL_W(40) DECL_W(41) DECL_W(42) DECL_W(43) DECL_W(44) DECL_W(45) DECL_W(46) DECL_W(47)
  DECL_W(48) DECL_W(49) DECL_W(50) DECL_W(51) DECL_W(52) DECL_W(53) DECL_W(54) DECL_W(55)
  DECL_W(56) DECL_W(57) DECL_W(58) DECL_W(59) DECL_W(60) DECL_W(61) DECL_W(62) DECL_W(63)

  float win0 = Win[lane];
  float win1 = Win[HH + lane];
  float bcj = bc[lane];
  float dwout = Wout[lane * 2 + 1] - Wout[lane * 2 + 0];
  const float dbout = bout[1] - bout[0];

  // Row 0 sees zero vertical hidden carry; step-0 hv is also zero.
#pragma unroll
  for (int c0 = 0; c0 < LL; ++c0) vrow[c0 * HH + lane] = 0.f;
  hvbuf[lane] = 0.f;  // buffer 0 feeds the very first step's LDS half

  const int* xb = x + b * (LL * LL);
  unsigned prevmask = 0u;                // previous row's spins (bit c = spin at col c)
  int spv = (lane < LL) ? xb[lane] : 0;  // prefetched row-0 spins
  float total_vec = 0.f;                 // per-lane partial of sum(logp)
  float hv = 0.f;                        // lane j's hv[j] (readlane source)

#pragma unroll 1
  for (int r = 0; r < LL; ++r) {
    const unsigned curmask =
        (unsigned)(__ballot(lane < LL && spv) & 0xffffffffull);
    if (r < LL - 1) spv = (lane < LL) ? xb[(r + 1) * LL + lane] : 0;

    const int odd = r & 1;
    const int d = odd ? -1 : 1;       // boustrophedon direction
    int c = odd ? (LL - 1) : 0;       // spatial column of scan step 0

#pragma unroll 2
    for (int k = 0; k < LL; ++k) {
      PIN_ALL_W

      // LDS half source: upper 32 hv values of the current parity buffer.
      // Issue the 8 uniform b128 reads FIRST — their latency (plus the
      // previous step's ds_write turnaround) hides under the readlane phase.
      const f32x4* hv4 = (const f32x4*)(hvbuf + (k & 1) * HH + 32);
      LOADG(0) LOADG(1) LOADG(2) LOADG(3) LOADG(4) LOADG(5) LOADG(6) LOADG(7)

      // Prefetch next step's vertical carry (off the serial chain).
      const int cn = (c + d) & (LL - 1);
      const float vjn = vrow[cn * HH + lane];

      float a0 = 0.f, a1 = 0.f, a2 = 0.f, a3 = 0.f;
      // Readlane half: i = 0..31 (VALU pipe, no LDS dependency).
      MV4R(0, 1, 2, 3)      MV4R(4, 5, 6, 7)      MV4R(8, 9, 10, 11)
      MV4R(12, 13, 14, 15)  MV4R(16, 17, 18, 19)  MV4R(20, 21, 22, 23)
      MV4R(24, 25, 26, 27)  MV4R(28, 29, 30, 31)
      // LDS half: i = 32..63 (uniform registers, fine-grained lgkmcnt).
      MV4L(0, 32, 33, 34, 35)  MV4L(1, 36, 37, 38, 39)
      MV4L(2, 40, 41, 42, 43)  MV4L(3, 44, 45, 46, 47)
      MV4L(4, 48, 49, 50, 51)  MV4L(5, 52, 53, 54, 55)
      MV4L(6, 56, 57, 58, 59)  MV4L(7, 60, 61, 62, 63)

      // newR @ Win: one-hot selects (spins are wave-uniform mask bits).
      float winc = 0.f;
      if (k > 0) {
        const unsigned sh = (curmask >> ((c - d) & 31)) & 1u;
        winc += sh ? win1 : win0;
      }
      if (r > 0) {
        const unsigned sv = (prevmask >> c) & 1u;
        winc += sv ? win1 : win0;
      }

      const float pre = ((a0 + a1) + (a2 + a3)) + bcj + winc;
      const float hnew = pre > 0.f ? pre : (__expf(pre) - 1.f);  // elu

      vrow[c * HH + lane] = hnew;        // vertical carry for next row (off-chain)
      pz[k * PZS + lane] = hnew * dwout; // deferred-dz contribution (off-chain)

      // hv for next step: register copy (readlane half) + LDS copy (ds half).
      // At k==31 the next step is the next row's step 0 (zero horiz carry).
      const float hvn = hnew + ((k < LL - 1) ? vjn : 0.f);
      hv = hvn;
      hvbuf[((k & 1) ^ 1) * HH + lane] = hvn;

      c = cn;
    }
    prevmask = curmask;

    // Row epilogue: transposed reduction (lane t sums pz row t&31; lanes
    // 32-63 duplicate via LDS broadcast, free).
    {
      const int kk = lane & 31;
      const float* pzr = pz + kk * PZS;
      float s0 = 0.f, s1 = 0.f, s2 = 0.f, s3 = 0.f;
#pragma unroll
      for (int g = 0; g < 16; ++g) {
        const f32x4 v = *(const f32x4*)(pzr + 4 * g);
        s0 += v[0]; s1 += v[1]; s2 += v[2]; s3 += v[3];
      }
      const float dz = ((s0 + s1) + (s2 + s3)) + dbout;  // z1 - z0 at step kk
      const int ck = odd ? (LL - 1 - kk) : kk;           // spatial column of step kk
      const unsigned spin = (curmask >> ck) & 1u;
      const float tt = __builtin_bit_cast(
          float, __builtin_bit_cast(unsigned, dz) ^ (spin << 31));
      float lpv = -(fmaxf(tt, 0.f) + __logf(1.f + __expf(-fabsf(tt))));
      lpv = (lpv == lpv) ? lpv : -35.0f;  // nan_to_num(nan=-35)
      total_vec += (lane < LL) ? lpv : 0.f;
    }
  }

  const float grand = wave_sum64(total_vec);
  if (lane == 0) out[b] = 0.5f * grand;  // LOGP_FACTOR * sum
}

extern "C" void kernel_launch(void* const* d_in, const int* in_sizes, int n_in,
                              void* d_out, int out_size, void* d_ws, size_t ws_size,
                              hipStream_t stream) {
  const int* x = (const int*)d_in[0];
  const float* Win = (const float*)d_in[1];
  const float* Wc = (const float*)d_in[2];
  const float* bc = (const float*)d_in[3];
  const float* Wout = (const float*)d_in[4];
  const float* bout = (const float*)d_in[5];
  float* out = (float*)d_out;
  rnn2d_kernel<<<dim3(out_size), dim3(64), 0, stream>>>(x, Win, Wc, bc, Wout, bout, out);
}